// Round 10
// baseline (375.153 us; speedup 1.0000x reference)
//
#include <hip/hip_runtime.h>

#define D 64
#define PSH 5                 // partition shift: 32 nodes / partition
#define PW 32                 // nodes per partition
#define EPB 8192              // edges per hist/scatter block (NB = ceil(E/EPB) <= 256)

// ---------- pass 1: per-block LDS histogram over partitions ----------
__global__ __launch_bounds__(256) void k_hist(const int* __restrict__ dst, int E,
                                              int* __restrict__ counts, int NP) {
    extern __shared__ int lh[];
    int t = threadIdx.x, b = blockIdx.x;
    for (int i = t; i < NP; i += 256) lh[i] = 0;
    __syncthreads();
    int base = b * EPB;
#pragma unroll
    for (int k = 0; k < EPB / 256; ++k) {
        int e = base + k * 256 + t;
        if (e < E) atomicAdd(&lh[dst[e] >> PSH], 1);
    }
    __syncthreads();
    for (int i = t; i < NP; i += 256) counts[(size_t)b * NP + i] = lh[i];
}

// ---------- pass 2a: per-bin exclusive scan over blocks ----------
__global__ __launch_bounds__(256) void k_scanA(int* __restrict__ counts, int NB, int NP,
                                               int* __restrict__ bin_total) {
    __shared__ int sh[256];
    int t = threadIdx.x, bin = blockIdx.x;
    int v = (t < NB) ? counts[(size_t)t * NP + bin] : 0;
    sh[t] = v;
    __syncthreads();
    for (int off = 1; off < 256; off <<= 1) {
        int u = (t >= off) ? sh[t - off] : 0;
        __syncthreads();
        sh[t] += u;
        __syncthreads();
    }
    if (t < NB) counts[(size_t)t * NP + bin] = sh[t] - v;  // exclusive within bin
    if (t == 255) bin_total[bin] = sh[255];
}

// ---------- pass 2b: single block scans bin totals (NP <= 2048) ----------
__global__ __launch_bounds__(1024) void k_scanB(const int* __restrict__ bin_total, int NP,
                                                int* __restrict__ bin_base) {
    __shared__ int sh[1024];
    int t = threadIdx.x;
    int i0 = 2 * t, i1 = 2 * t + 1;
    int v0 = (i0 < NP) ? bin_total[i0] : 0;
    int v1 = (i1 < NP) ? bin_total[i1] : 0;
    int s = v0 + v1;
    sh[t] = s;
    __syncthreads();
    for (int off = 1; off < 1024; off <<= 1) {
        int u = (t >= off) ? sh[t - off] : 0;
        __syncthreads();
        sh[t] += u;
        __syncthreads();
    }
    int excl = sh[t] - s;
    if (i0 < NP) bin_base[i0] = excl;
    if (i1 < NP) bin_base[i1] = excl + v0;
    if (t == 1023) bin_base[NP] = sh[1023];   // = E
}

// ---------- pass 3: scatter with LDS cursors (no global atomics) ----------
__global__ __launch_bounds__(256) void k_scatter(const int* __restrict__ src,
        const int* __restrict__ dst, int E, const int* __restrict__ counts,
        const int* __restrict__ bin_base, int NP, int* __restrict__ csr_e) {
    extern __shared__ int cur[];
    int t = threadIdx.x, b = blockIdx.x;
    for (int i = t; i < NP; i += 256)
        cur[i] = counts[(size_t)b * NP + i] + bin_base[i];
    __syncthreads();
    int base = b * EPB;
#pragma unroll
    for (int k = 0; k < EPB / 256; ++k) {
        int e = base + k * 256 + t;
        if (e < E) {
            int s = src[e], d = dst[e];
            int pos = atomicAdd(&cur[d >> PSH], 1);          // LDS atomic
            csr_e[pos] = s | ((d & (PW - 1)) << 16);         // src<65536, 5-bit local dst
        }
    }
}

// ---------- per-partition degree -> dinv (from sorted edges, no atomics) ----------
__global__ __launch_bounds__(64) void k_pdeg(const int* __restrict__ csr_e,
                                             const int* __restrict__ bin_base,
                                             float* __restrict__ dinv, int n) {
    __shared__ int cnt[PW];
    int t = threadIdx.x, p = blockIdx.x;
    if (t < PW) cnt[t] = 0;
    __syncthreads();
    int beg = bin_base[p], end = bin_base[p + 1];
    for (int i = beg + t; i < end; i += 64) atomicAdd(&cnt[csr_e[i] >> 16], 1);
    __syncthreads();
    int node = p * PW + t;
    if (t < PW && node < n) dinv[node] = rsqrtf((float)(cnt[t] + 1));  // +1 self-loop
}

// ---------- layer-1 gather: block per partition, LDS fp32 accumulate ----------
__global__ __launch_bounds__(256) void k_pgather(const float* __restrict__ x,
        const float* __restrict__ dinv, const int* __restrict__ csr_e,
        const int* __restrict__ bin_base, float* __restrict__ agg, int n) {
    __shared__ float lagg[PW][D + 4];   // pad 68 floats: spreads banks
    __shared__ float ldv[PW];
    int t = threadIdx.x, p = blockIdx.x;
    for (int i = t; i < PW * (D + 4); i += 256) ((float*)lagg)[i] = 0.0f;
    if (t < PW) {
        int node = p * PW + t;
        ldv[t] = (node < n) ? dinv[node] : 0.0f;
    }
    __syncthreads();
    int beg = bin_base[p], end = bin_base[p + 1];
    int g = t >> 4, dg = t & 15;        // 16 edge-groups x 16 dim-lanes
    for (int i = beg + g; i < end; i += 16) {
        int e = csr_e[i];               // same addr across 16 lanes -> broadcast
        int u = e & 0xFFFF, d = e >> 16;
        float nrm = dinv[u] * ldv[d];
        float4 xv = *(const float4*)&x[(size_t)u * D + dg * 4];
        atomicAdd(&lagg[d][dg * 4 + 0], xv.x * nrm);
        atomicAdd(&lagg[d][dg * 4 + 1], xv.y * nrm);
        atomicAdd(&lagg[d][dg * 4 + 2], xv.z * nrm);
        atomicAdd(&lagg[d][dg * 4 + 3], xv.w * nrm);
    }
    __syncthreads();
    // self-loop + coalesced writeout: node r = t>>3, dims seg*8..seg*8+7
    int r = t >> 3, seg = t & 7;
    int node = p * PW + r;
    if (node < n) {
        float dv = ldv[r], w = dv * dv;
        float4 a0 = *(float4*)&lagg[r][seg * 8];
        float4 a1 = *(float4*)&lagg[r][seg * 8 + 4];
        float4 x0 = *(const float4*)&x[(size_t)node * D + seg * 8];
        float4 x1 = *(const float4*)&x[(size_t)node * D + seg * 8 + 4];
        a0.x += x0.x * w; a0.y += x0.y * w; a0.z += x0.z * w; a0.w += x0.w * w;
        a1.x += x1.x * w; a1.y += x1.y * w; a1.z += x1.z * w; a1.w += x1.w * w;
        *(float4*)&agg[(size_t)node * D + seg * 8] = a0;
        *(float4*)&agg[(size_t)node * D + seg * 8 + 4] = a1;
    }
}

// ---------- dense GEMM + relu + W2-dot: wave per node, 16 nodes/wave ----------
#define NPW 16
__global__ __launch_bounds__(256) void k_gemm(
        const float* __restrict__ agg, const float* __restrict__ dinv,
        const float* __restrict__ W1, const float* __restrict__ b1,
        const float* __restrict__ W2, float* __restrict__ sd, int n) {
    __shared__ float lrow[4][D];
    int tid = threadIdx.x;
    int wave = tid >> 6, lane = tid & 63;
    float w1c[D];
#pragma unroll
    for (int d = 0; d < D; ++d) w1c[d] = W1[d * D + lane];
    float b1l = b1[lane], w2l = W2[lane];
    int v0 = (blockIdx.x * 4 + wave) * NPW;
    for (int k = 0; k < NPW; ++k) {
        int v = v0 + k;
        if (v >= n) break;
        lrow[wave][lane] = agg[(size_t)v * D + lane];  // coalesced 256B
        __builtin_amdgcn_wave_barrier();
        float h = b1l;
#pragma unroll
        for (int db = 0; db < D; db += 4) {
            float4 r = *(const float4*)&lrow[wave][db];  // broadcast ds_read_b128
            h = fmaf(r.x, w1c[db], h);
            h = fmaf(r.y, w1c[db + 1], h);
            h = fmaf(r.z, w1c[db + 2], h);
            h = fmaf(r.w, w1c[db + 3], h);
        }
        float tt = fmaxf(h, 0.0f) * w2l;
#pragma unroll
        for (int off = 1; off <= 32; off <<= 1) tt += __shfl_xor(tt, off, 64);
        if (lane == 0) sd[v] = tt * dinv[v];  // s[v] * dinv[v]
        __builtin_amdgcn_wave_barrier();
    }
}

// ---------- layer-2: block per partition, LDS scalar accumulate ----------
__global__ __launch_bounds__(256) void k_pout(const float* __restrict__ sd,
        const float* __restrict__ dinv, const int* __restrict__ csr_e,
        const int* __restrict__ bin_base, const float* __restrict__ b2,
        float* __restrict__ out, int n) {
    __shared__ float ssum[PW];
    int t = threadIdx.x, p = blockIdx.x;
    if (t < PW) ssum[t] = 0.0f;
    __syncthreads();
    int beg = bin_base[p], end = bin_base[p + 1];
    for (int i = beg + t; i < end; i += 256) {
        int e = csr_e[i];
        atomicAdd(&ssum[e >> 16], sd[e & 0xFFFF]);
    }
    __syncthreads();
    int node = p * PW + t;
    if (t < PW && node < n) out[node] = b2[0] + (ssum[t] + sd[node]) * dinv[node];
}

extern "C" void kernel_launch(void* const* d_in, const int* in_sizes, int n_in,
                              void* d_out, int out_size, void* d_ws, size_t ws_size,
                              hipStream_t stream) {
    const float* x  = (const float*)d_in[0];
    const int*   ei = (const int*)d_in[1];
    const float* W1 = (const float*)d_in[2];
    const float* b1 = (const float*)d_in[3];
    const float* W2 = (const float*)d_in[4];
    const float* b2 = (const float*)d_in[5];

    int n = in_sizes[0] / D;   // 50000
    int E = in_sizes[1] / 2;   // 800000
    const int* src = ei;
    const int* dst = ei + E;

    int NP = (n + PW - 1) / PW;      // 1563 partitions
    int NB = (E + EPB - 1) / EPB;    // 98 hist/scatter blocks

    char* ws = (char*)d_ws;
    auto take = [&](size_t bytes) {
        char* p = ws;
        ws += (bytes + 255) & ~(size_t)255;
        return p;
    };
    int*   counts    = (int*)take((size_t)NB * NP * sizeof(int));
    int*   bin_total = (int*)take((size_t)NP * sizeof(int));
    int*   bin_base  = (int*)take((size_t)(NP + 1) * sizeof(int));
    int*   csr_e     = (int*)take((size_t)E * sizeof(int));
    float* dinv      = (float*)take((size_t)n * sizeof(float));
    float* sd        = (float*)take((size_t)n * sizeof(float));
    float* agg       = (float*)take((size_t)n * D * sizeof(float));

    float* out = (float*)d_out;
    size_t ldsNP = (size_t)NP * sizeof(int);

    k_hist<<<NB, 256, ldsNP, stream>>>(dst, E, counts, NP);
    k_scanA<<<NP, 256, 0, stream>>>(counts, NB, NP, bin_total);
    k_scanB<<<1, 1024, 0, stream>>>(bin_total, NP, bin_base);
    k_scatter<<<NB, 256, ldsNP, stream>>>(src, dst, E, counts, bin_base, NP, csr_e);

    k_pdeg<<<NP, 64, 0, stream>>>(csr_e, bin_base, dinv, n);
    k_pgather<<<NP, 256, 0, stream>>>(x, dinv, csr_e, bin_base, agg, n);
    k_gemm<<<(n + 4 * NPW - 1) / (4 * NPW), 256, 0, stream>>>(agg, dinv, W1, b1,
                                                              W2, sd, n);
    k_pout<<<NP, 256, 0, stream>>>(sd, dinv, csr_e, bin_base, b2, out, n);
}

// Round 11
// 92.386 us; speedup vs baseline: 4.0607x; 4.0607x over previous
//
#include <hip/hip_runtime.h>

#define D 64
#define PW2 256               // nodes per partition (fine-sort block)
#define PSH2 8
#define EPB 4096              // edges per hist/scatter block; NB = ceil(E/EPB) <= 256

// ---------- pass 1: per-block LDS histogram over 196 partitions ----------
__global__ __launch_bounds__(256) void k_hist(const int* __restrict__ dst, int E,
                                              int* __restrict__ counts, int NP) {
    extern __shared__ int lh[];
    int t = threadIdx.x, b = blockIdx.x;
    for (int i = t; i < NP; i += 256) lh[i] = 0;
    __syncthreads();
    int base = b * EPB;
#pragma unroll
    for (int k = 0; k < EPB / 256; ++k) {
        int e = base + k * 256 + t;
        if (e < E) atomicAdd(&lh[dst[e] >> PSH2], 1);
    }
    __syncthreads();
    for (int i = t; i < NP; i += 256) counts[(size_t)b * NP + i] = lh[i];
}

// ---------- pass 2a: per-bin exclusive scan over blocks (NB <= 256) ----------
__global__ __launch_bounds__(256) void k_scanA(int* __restrict__ counts, int NB, int NP,
                                               int* __restrict__ bin_total) {
    __shared__ int sh[256];
    int t = threadIdx.x, bin = blockIdx.x;
    int v = (t < NB) ? counts[(size_t)t * NP + bin] : 0;
    sh[t] = v;
    __syncthreads();
    for (int off = 1; off < 256; off <<= 1) {
        int u = (t >= off) ? sh[t - off] : 0;
        __syncthreads();
        sh[t] += u;
        __syncthreads();
    }
    if (t < NB) counts[(size_t)t * NP + bin] = sh[t] - v;  // exclusive within bin
    if (t == 255) bin_total[bin] = sh[255];
}

// ---------- pass 2b: single block scans 196 bin totals ----------
__global__ __launch_bounds__(256) void k_scanB(const int* __restrict__ bin_total, int NP,
                                               int* __restrict__ bin_base) {
    __shared__ int sh[256];
    int t = threadIdx.x;
    int v = (t < NP) ? bin_total[t] : 0;
    sh[t] = v;
    __syncthreads();
    for (int off = 1; off < 256; off <<= 1) {
        int u = (t >= off) ? sh[t - off] : 0;
        __syncthreads();
        sh[t] += u;
        __syncthreads();
    }
    if (t < NP) bin_base[t] = sh[t] - v;
    if (t == 255) bin_base[NP] = sh[255];   // = E
}

// ---------- pass 3: coarse scatter with LDS cursors (no global atomics) ----------
__global__ __launch_bounds__(256) void k_scatter(const int* __restrict__ src,
        const int* __restrict__ dst, int E, const int* __restrict__ counts,
        const int* __restrict__ bin_base, int NP, int* __restrict__ csr_e) {
    extern __shared__ int cur[];
    int t = threadIdx.x, b = blockIdx.x;
    for (int i = t; i < NP; i += 256)
        cur[i] = counts[(size_t)b * NP + i] + bin_base[i];
    __syncthreads();
    int base = b * EPB;
#pragma unroll
    for (int k = 0; k < EPB / 256; ++k) {
        int e = base + k * 256 + t;
        if (e < E) {
            int s = src[e], d = dst[e];
            int pos = atomicAdd(&cur[d >> PSH2], 1);      // LDS atomic
            csr_e[pos] = s | ((d & (PW2 - 1)) << 16);     // src<2^16, local dst 8b
        }
    }
}

// ---------- pass 4: fine sort within partition -> csr_src, row_ptr, dinv ----------
__global__ __launch_bounds__(256) void k_sort2(const int* __restrict__ csr_e,
        const int* __restrict__ bin_base, int n,
        int* __restrict__ csr_src, int* __restrict__ row_ptr,
        float* __restrict__ dinv) {
    __shared__ int cnt[PW2];
    __shared__ int sh[PW2];
    __shared__ int cursor[PW2];
    int t = threadIdx.x, p = blockIdx.x;
    cnt[t] = 0;
    __syncthreads();
    int beg = bin_base[p], end = bin_base[p + 1];
    for (int i = beg + t; i < end; i += 256) atomicAdd(&cnt[csr_e[i] >> 16], 1);
    __syncthreads();
    int val = cnt[t];
    sh[t] = val;
    __syncthreads();
    for (int off = 1; off < 256; off <<= 1) {
        int u = (t >= off) ? sh[t - off] : 0;
        __syncthreads();
        sh[t] += u;
        __syncthreads();
    }
    int excl = sh[t] - val;
    cursor[t] = beg + excl;
    int node = p * PW2 + t;
    if (node <= n) {
        row_ptr[node] = beg + excl;              // node==n gets E (last partition)
        if (node < n) dinv[node] = rsqrtf((float)(val + 1));  // +1 self-loop
    }
    __syncthreads();
    for (int i = beg + t; i < end; i += 256) {
        int e = csr_e[i];
        int q = atomicAdd(&cursor[e >> 16], 1);  // LDS atomic
        csr_src[q] = e & 0xFFFF;
    }
}

// ---------- gather: 1 node/wave, 4 edge-slots x 16 dim-groups, 4-deep pipeline ----------
__global__ __launch_bounds__(256) void k_gather(
        const float* __restrict__ x, const float* __restrict__ dinv,
        const int* __restrict__ row_ptr, const int* __restrict__ csr_src,
        float* __restrict__ agg, int n) {
    int tid = threadIdx.x;
    int wave = tid >> 6, lane = tid & 63;
    int eg = lane >> 4, dg = lane & 15;
    int v = blockIdx.x * 4 + wave;
    if (v >= n) return;
    float dv = dinv[v];
    int beg = row_ptr[v], end = row_ptr[v + 1];

    float4 acc = make_float4(0.f, 0.f, 0.f, 0.f);
    if (eg == 0) {  // self-loop term
        float4 xv = *(const float4*)&x[(size_t)v * D + dg * 4];
        float w = dv * dv;
        acc.x = xv.x * w; acc.y = xv.y * w; acc.z = xv.z * w; acc.w = xv.w * w;
    }
    int base = beg;
    for (; base + 16 <= end; base += 16) {
        int u0 = csr_src[base + eg];
        int u1 = csr_src[base + 4 + eg];
        int u2 = csr_src[base + 8 + eg];
        int u3 = csr_src[base + 12 + eg];
        float n0 = dinv[u0] * dv, n1 = dinv[u1] * dv;
        float n2 = dinv[u2] * dv, n3 = dinv[u3] * dv;
        float4 x0 = *(const float4*)&x[(size_t)u0 * D + dg * 4];
        float4 x1 = *(const float4*)&x[(size_t)u1 * D + dg * 4];
        float4 x2 = *(const float4*)&x[(size_t)u2 * D + dg * 4];
        float4 x3 = *(const float4*)&x[(size_t)u3 * D + dg * 4];
        acc.x = fmaf(x0.x, n0, acc.x); acc.y = fmaf(x0.y, n0, acc.y);
        acc.z = fmaf(x0.z, n0, acc.z); acc.w = fmaf(x0.w, n0, acc.w);
        acc.x = fmaf(x1.x, n1, acc.x); acc.y = fmaf(x1.y, n1, acc.y);
        acc.z = fmaf(x1.z, n1, acc.z); acc.w = fmaf(x1.w, n1, acc.w);
        acc.x = fmaf(x2.x, n2, acc.x); acc.y = fmaf(x2.y, n2, acc.y);
        acc.z = fmaf(x2.z, n2, acc.z); acc.w = fmaf(x2.w, n2, acc.w);
        acc.x = fmaf(x3.x, n3, acc.x); acc.y = fmaf(x3.y, n3, acc.y);
        acc.w = fmaf(x3.w, n3, acc.w); acc.z = fmaf(x3.z, n3, acc.z);
    }
    for (; base + 8 <= end; base += 8) {
        int u0 = csr_src[base + eg];
        int u1 = csr_src[base + 4 + eg];
        float n0 = dinv[u0] * dv, n1 = dinv[u1] * dv;
        float4 x0 = *(const float4*)&x[(size_t)u0 * D + dg * 4];
        float4 x1 = *(const float4*)&x[(size_t)u1 * D + dg * 4];
        acc.x = fmaf(x0.x, n0, acc.x); acc.y = fmaf(x0.y, n0, acc.y);
        acc.z = fmaf(x0.z, n0, acc.z); acc.w = fmaf(x0.w, n0, acc.w);
        acc.x = fmaf(x1.x, n1, acc.x); acc.y = fmaf(x1.y, n1, acc.y);
        acc.z = fmaf(x1.z, n1, acc.z); acc.w = fmaf(x1.w, n1, acc.w);
    }
    for (; base < end; base += 4) {
        int idx = base + eg;
        if (idx < end) {
            int u = csr_src[idx];
            float nrm = dinv[u] * dv;
            float4 xv = *(const float4*)&x[(size_t)u * D + dg * 4];
            acc.x = fmaf(xv.x, nrm, acc.x); acc.y = fmaf(xv.y, nrm, acc.y);
            acc.z = fmaf(xv.z, nrm, acc.z); acc.w = fmaf(xv.w, nrm, acc.w);
        }
    }
#pragma unroll
    for (int off = 16; off <= 32; off <<= 1) {
        acc.x += __shfl_xor(acc.x, off, 64);
        acc.y += __shfl_xor(acc.y, off, 64);
        acc.z += __shfl_xor(acc.z, off, 64);
        acc.w += __shfl_xor(acc.w, off, 64);
    }
    if (eg == 0) *(float4*)&agg[(size_t)v * D + dg * 4] = acc;
}

// ---------- dense GEMM + relu + W2-dot: wave per node, 16 nodes/wave ----------
#define NPW 16
__global__ __launch_bounds__(256) void k_gemm(
        const float* __restrict__ agg, const float* __restrict__ dinv,
        const float* __restrict__ W1, const float* __restrict__ b1,
        const float* __restrict__ W2, float* __restrict__ sd, int n) {
    __shared__ float lrow[4][D];
    int tid = threadIdx.x;
    int wave = tid >> 6, lane = tid & 63;
    float w1c[D];
#pragma unroll
    for (int d = 0; d < D; ++d) w1c[d] = W1[d * D + lane];
    float b1l = b1[lane], w2l = W2[lane];
    int v0 = (blockIdx.x * 4 + wave) * NPW;
    for (int k = 0; k < NPW; ++k) {
        int v = v0 + k;
        if (v >= n) break;
        lrow[wave][lane] = agg[(size_t)v * D + lane];  // coalesced 256B
        __builtin_amdgcn_wave_barrier();
        float h = b1l;
#pragma unroll
        for (int db = 0; db < D; db += 4) {
            float4 r = *(const float4*)&lrow[wave][db];  // broadcast ds_read_b128
            h = fmaf(r.x, w1c[db], h);
            h = fmaf(r.y, w1c[db + 1], h);
            h = fmaf(r.z, w1c[db + 2], h);
            h = fmaf(r.w, w1c[db + 3], h);
        }
        float tt = fmaxf(h, 0.0f) * w2l;
#pragma unroll
        for (int off = 1; off <= 32; off <<= 1) tt += __shfl_xor(tt, off, 64);
        if (lane == 0) sd[v] = tt * dinv[v];  // s[v] * dinv[v]
        __builtin_amdgcn_wave_barrier();
    }
}

// ---------- layer-2: 8 lanes per node gather over CSR ----------
__global__ __launch_bounds__(256) void k_out(const float* __restrict__ sd,
        const float* __restrict__ dinv, const int* __restrict__ row_ptr,
        const int* __restrict__ csr_src, const float* __restrict__ b2,
        float* __restrict__ out, int n) {
    int t = blockIdx.x * blockDim.x + threadIdx.x;
    int v = t >> 3, r = t & 7;
    if (v >= n) return;
    int beg = row_ptr[v], end = row_ptr[v + 1];
    float a = (r == 0) ? sd[v] : 0.0f;  // self-loop
    for (int i = beg + r; i < end; i += 8) a += sd[csr_src[i]];
    a += __shfl_xor(a, 1, 64);
    a += __shfl_xor(a, 2, 64);
    a += __shfl_xor(a, 4, 64);
    if (r == 0) out[v] = b2[0] + a * dinv[v];
}

extern "C" void kernel_launch(void* const* d_in, const int* in_sizes, int n_in,
                              void* d_out, int out_size, void* d_ws, size_t ws_size,
                              hipStream_t stream) {
    const float* x  = (const float*)d_in[0];
    const int*   ei = (const int*)d_in[1];
    const float* W1 = (const float*)d_in[2];
    const float* b1 = (const float*)d_in[3];
    const float* W2 = (const float*)d_in[4];
    const float* b2 = (const float*)d_in[5];

    int n = in_sizes[0] / D;   // 50000
    int E = in_sizes[1] / 2;   // 800000
    const int* src = ei;
    const int* dst = ei + E;

    int NP = (n + PW2 - 1) / PW2;    // 196 partitions
    int NB = (E + EPB - 1) / EPB;    // 196 edge blocks (<= 256)

    char* ws = (char*)d_ws;
    auto take = [&](size_t bytes) {
        char* p = ws;
        ws += (bytes + 255) & ~(size_t)255;
        return p;
    };
    int*   counts    = (int*)take((size_t)NB * NP * sizeof(int));
    int*   bin_total = (int*)take((size_t)NP * sizeof(int));
    int*   bin_base  = (int*)take((size_t)(NP + 1) * sizeof(int));
    int*   csr_e     = (int*)take((size_t)E * sizeof(int));
    int*   csr_src   = (int*)take((size_t)E * sizeof(int));
    int*   row_ptr   = (int*)take((size_t)(n + 1) * sizeof(int));
    float* dinv      = (float*)take((size_t)n * sizeof(float));
    float* sd        = (float*)take((size_t)n * sizeof(float));
    float* agg       = (float*)take((size_t)n * D * sizeof(float));

    float* out = (float*)d_out;
    size_t ldsNP = (size_t)NP * sizeof(int);

    k_hist<<<NB, 256, ldsNP, stream>>>(dst, E, counts, NP);
    k_scanA<<<NP, 256, 0, stream>>>(counts, NB, NP, bin_total);
    k_scanB<<<1, 256, 0, stream>>>(bin_total, NP, bin_base);
    k_scatter<<<NB, 256, ldsNP, stream>>>(src, dst, E, counts, bin_base, NP, csr_e);
    k_sort2<<<NP, 256, 0, stream>>>(csr_e, bin_base, n, csr_src, row_ptr, dinv);

    k_gather<<<(n + 3) / 4, 256, 0, stream>>>(x, dinv, row_ptr, csr_src, agg, n);
    k_gemm<<<(n + 4 * NPW - 1) / (4 * NPW), 256, 0, stream>>>(agg, dinv, W1, b1,
                                                              W2, sd, n);
    k_out<<<((size_t)n * 8 + 255) / 256, 256, 0, stream>>>(sd, dinv, row_ptr, csr_src,
                                                           b2, out, n);
}